// Round 9
// baseline (189.028 us; speedup 1.0000x reference)
//
#include <hip/hip_runtime.h>

#define THREADS 512
#define HW 16384        // H*W per (b,c) row
#define K_SEL 8192u     // k = 0.5 * H * W
#define NB1 2048        // pass-1: abs bits [30:20]
#define NB2 1024        // pass-2: bits [19:10]
#define NB3 1024        // pass-3: bits [9:0]
#define VPT 8           // uint4 per thread (32 floats); THREADS*VPT*4 == HW
#define CAP 3072        // candidate-list capacity (fallback to full scan if exceeded)

static_assert(THREADS * VPT * 4 == HW, "row tiling");

typedef unsigned uint32x4 __attribute__((ext_vector_type(4)));  // NT-store-compatible

// Two-stage parallel bin search, executed by wave 0 only; result broadcast
// via LDS. Bins ascend in value; finds the bin holding the kRem-th LARGEST
// element and the residual rank within it. ALL cross-lane ops are convergent
// (every lane of wave 0 executes them); only the final LDS write is guarded.
template <int NBINS>
__device__ __forceinline__ void find_bin_wave0(const unsigned* __restrict__ hist,
                                               unsigned kRem, unsigned* __restrict__ bc) {
  constexpr int bpl = NBINS >> 6;             // bins per lane
  const int lane = (int)(threadIdx.x & 63);
  const int base = lane * bpl;
  // Stage 1: bank-rotated chunk sums (conflict-free), suffix-scan over lanes.
  unsigned s = 0;
#pragma unroll
  for (int j = 0; j < bpl; ++j) s += hist[base + ((j + lane) & (bpl - 1))];
  unsigned suf = s;
#pragma unroll
  for (int off = 1; off < 64; off <<= 1) {
    unsigned w = __shfl_down(suf, off);
    if (lane + off < 64) suf += w;
  }
  const unsigned cumAbove = suf - s;
  const bool hit = (cumAbove < kRem) && (kRem <= suf);
  const unsigned long long m = __ballot(hit);
  const int tl = (int)__builtin_ctzll(m);     // unique target chunk
  const unsigned cumTl = __shfl(cumAbove, tl);
  // Stage 2: suffix-scan within the target chunk (lane groups of bpl work
  // redundantly on the same addresses -> LDS broadcast, conflict-free).
  const int j = lane & (bpl - 1);
  const unsigned h = hist[tl * bpl + j];
  unsigned sufc = h;
#pragma unroll
  for (int off = 1; off < 32; off <<= 1) {
    if (off < bpl) {
      unsigned w = __shfl_down(sufc, off);
      if (j + off < bpl) sufc += w;
    }
  }
  const unsigned cumW = sufc - h;
  const bool hit2 = ((cumTl + cumW) < kRem) && (kRem <= cumTl + cumW + h);
  const unsigned long long m2 = __ballot(hit2);
  const int jl = (int)__builtin_ctzll(m2) & (bpl - 1);
  const unsigned kw = __shfl(cumW, jl);       // convergent: all lanes execute
  if (lane == 0) {
    bc[0] = (unsigned)(tl * bpl + jl);
    bc[1] = kRem - cumTl - kw;
  }
}

extern "C" __global__ __launch_bounds__(THREADS, 8)
void sparsify_topk_kernel(const float* __restrict__ x, float* __restrict__ out) {
  __shared__ unsigned h1[NB1];
  __shared__ unsigned h2[NB2];
  __shared__ unsigned h3[NB3];
  __shared__ unsigned list[CAP];   // candidate |x| bit patterns (top-11 == T1)
  __shared__ unsigned bc[2];
  __shared__ unsigned cnt;

  const int t = (int)threadIdx.x;
  const size_t rowOff = (size_t)blockIdx.x * (HW / 4);
  const uint4* src = (const uint4*)x + rowOff;
  uint32x4*    dst = (uint32x4*)out + rowOff;

  // Issue the row load first (latency hides under hist zeroing + barrier).
  uint4 v[VPT];
#pragma unroll
  for (int i = 0; i < VPT; ++i) v[i] = src[i * THREADS + t];

  // Zero all hists + list counter.
#pragma unroll
  for (int i = 0; i < NB1 / THREADS; ++i) h1[t + i * THREADS] = 0;
#pragma unroll
  for (int i = 0; i < NB2 / THREADS; ++i) h2[t + i * THREADS] = 0;
#pragma unroll
  for (int i = 0; i < NB3 / THREADS; ++i) h3[t + i * THREADS] = 0;
  if (t == 0) cnt = 0;
  __syncthreads();

  // P1: bits [30:20] -> h1
#pragma unroll
  for (int i = 0; i < VPT; ++i) {
    atomicAdd(&h1[(v[i].x & 0x7fffffffu) >> 20], 1u);
    atomicAdd(&h1[(v[i].y & 0x7fffffffu) >> 20], 1u);
    atomicAdd(&h1[(v[i].z & 0x7fffffffu) >> 20], 1u);
    atomicAdd(&h1[(v[i].w & 0x7fffffffu) >> 20], 1u);
  }
  __syncthreads();
  if (t < 64) find_bin_wave0<NB1>(h1, K_SEL, bc);
  __syncthreads();
  const unsigned T1 = bc[0];
  unsigned kRem = bc[1];

  // P2: among (a>>20)==T1 (~2-5% of elements): build h2 (always complete)
  // AND append candidate to list (guarded; overflow -> fallback below).
#pragma unroll
  for (int i = 0; i < VPT; ++i) {
    unsigned a;
#define P2_ONE(comp)                                                        \
    a = v[i].comp & 0x7fffffffu;                                            \
    if ((a >> 20) == T1) {                                                  \
      atomicAdd(&h2[(a >> 10) & (NB2 - 1)], 1u);                            \
      const unsigned idx = atomicAdd(&cnt, 1u);                             \
      if (idx < CAP) list[idx] = a;                                         \
    }
    P2_ONE(x) P2_ONE(y) P2_ONE(z) P2_ONE(w)
#undef P2_ONE
  }
  __syncthreads();
  if (t < 64) find_bin_wave0<NB2>(h2, kRem, bc);
  __syncthreads();
  const unsigned pref2 = (T1 << 10) | bc[0];   // == a>>10 of threshold
  kRem = bc[1];
  const unsigned nCand = cnt;                  // block-uniform after barrier

  // P3: bits [9:0] of elements with (a>>10)==pref2 -> h3.
  // Common path: scan the small candidate list. Fallback (list overflow):
  // rescan the full row from registers (exact for adversarial inputs).
  if (nCand <= CAP) {
    for (unsigned i = t; i < nCand; i += THREADS) {
      const unsigned a = list[i];
      if ((a >> 10) == pref2) atomicAdd(&h3[a & (NB3 - 1)], 1u);
    }
  } else {
#pragma unroll
    for (int i = 0; i < VPT; ++i) {
      unsigned a;
      a = v[i].x & 0x7fffffffu; if ((a >> 10) == pref2) atomicAdd(&h3[a & (NB3 - 1)], 1u);
      a = v[i].y & 0x7fffffffu; if ((a >> 10) == pref2) atomicAdd(&h3[a & (NB3 - 1)], 1u);
      a = v[i].z & 0x7fffffffu; if ((a >> 10) == pref2) atomicAdd(&h3[a & (NB3 - 1)], 1u);
      a = v[i].w & 0x7fffffffu; if ((a >> 10) == pref2) atomicAdd(&h3[a & (NB3 - 1)], 1u);
    }
  }
  __syncthreads();
  if (t < 64) find_bin_wave0<NB3>(h3, kRem, bc);
  __syncthreads();
  const unsigned thr = (pref2 << 10) | bc[0];  // exact k-th largest |x| bits

  // Masked non-temporal store (>= keeps ties, same as reference). Output has
  // zero reuse -> keep it out of L2/L3 so the input stays cached.
#pragma unroll
  for (int i = 0; i < VPT; ++i) {
    const uint4 w = v[i];
    uint32x4 o;
    o.x = ((w.x & 0x7fffffffu) >= thr) ? w.x : 0u;
    o.y = ((w.y & 0x7fffffffu) >= thr) ? w.y : 0u;
    o.z = ((w.z & 0x7fffffffu) >= thr) ? w.z : 0u;
    o.w = ((w.w & 0x7fffffffu) >= thr) ? w.w : 0u;
    __builtin_nontemporal_store(o, &dst[i * THREADS + t]);
  }
}

extern "C" void kernel_launch(void* const* d_in, const int* in_sizes, int n_in,
                              void* d_out, int out_size, void* d_ws, size_t ws_size,
                              hipStream_t stream) {
  (void)n_in; (void)d_ws; (void)ws_size; (void)out_size;
  const float* x = (const float*)d_in[0];
  float* out = (float*)d_out;
  const int rows = in_sizes[0] / HW;   // 4096
  sparsify_topk_kernel<<<dim3(rows), dim3(THREADS), 0, stream>>>(x, out);
}

// Round 10
// 96.906 us; speedup vs baseline: 1.9506x; 1.9506x over previous
//
#include <hip/hip_runtime.h>

#define THREADS 512
#define HW 16384        // H*W per (b,c) row
#define K_SEL 8192u     // k = 0.5 * H * W
#define NB1 2048        // pass-1: abs bits [30:20]
#define NB2 1024        // pass-2: bits [19:10]
#define NB3 1024        // pass-3: bits [9:0]
#define VPT 8           // uint4 per thread (32 floats); THREADS*VPT*4 == HW

static_assert(THREADS * VPT * 4 == HW, "row tiling");

typedef unsigned uint32x4 __attribute__((ext_vector_type(4)));  // NT-store-compatible

// Two-stage parallel bin search, executed by wave 0 only; result broadcast
// via LDS. Bins ascend in value; finds the bin holding the kRem-th LARGEST
// element and the residual rank within it. ALL cross-lane ops are convergent
// (every lane of wave 0 executes them); only the final LDS write is guarded.
template <int NBINS>
__device__ __forceinline__ void find_bin_wave0(const unsigned* __restrict__ hist,
                                               unsigned kRem, unsigned* __restrict__ bc) {
  constexpr int bpl = NBINS >> 6;             // bins per lane
  const int lane = (int)(threadIdx.x & 63);
  const int base = lane * bpl;
  // Stage 1: bank-rotated chunk sums (conflict-free), suffix-scan over lanes.
  unsigned s = 0;
#pragma unroll
  for (int j = 0; j < bpl; ++j) s += hist[base + ((j + lane) & (bpl - 1))];
  unsigned suf = s;
#pragma unroll
  for (int off = 1; off < 64; off <<= 1) {
    unsigned w = __shfl_down(suf, off);
    if (lane + off < 64) suf += w;
  }
  const unsigned cumAbove = suf - s;
  const bool hit = (cumAbove < kRem) && (kRem <= suf);
  const unsigned long long m = __ballot(hit);
  const int tl = (int)__builtin_ctzll(m);     // unique target chunk
  const unsigned cumTl = __shfl(cumAbove, tl);
  // Stage 2: suffix-scan within the target chunk (lane groups of bpl work
  // redundantly on the same addresses -> LDS broadcast, conflict-free).
  const int j = lane & (bpl - 1);
  const unsigned h = hist[tl * bpl + j];
  unsigned sufc = h;
#pragma unroll
  for (int off = 1; off < 32; off <<= 1) {
    if (off < bpl) {
      unsigned w = __shfl_down(sufc, off);
      if (j + off < bpl) sufc += w;
    }
  }
  const unsigned cumW = sufc - h;
  const bool hit2 = ((cumTl + cumW) < kRem) && (kRem <= cumTl + cumW + h);
  const unsigned long long m2 = __ballot(hit2);
  const int jl = (int)__builtin_ctzll(m2) & (bpl - 1);
  const unsigned kw = __shfl(cumW, jl);       // convergent: all lanes execute
  if (lane == 0) {
    bc[0] = (unsigned)(tl * bpl + jl);
    bc[1] = kRem - cumTl - kw;
  }
}

extern "C" __global__ __launch_bounds__(THREADS, 8)
void sparsify_topk_kernel(const float* __restrict__ x, float* __restrict__ out) {
  __shared__ unsigned h1[NB1];
  __shared__ unsigned h2[NB2];
  __shared__ unsigned h3[NB3];
  __shared__ unsigned bc[2];

  const int t = (int)threadIdx.x;
  const size_t rowOff = (size_t)blockIdx.x * (HW / 4);
  const uint4*    src = (const uint4*)x + rowOff;
  uint32x4*       dst = (uint32x4*)out + rowOff;

  // Issue the row load first (latency hides under hist zeroing + barrier).
  uint4 v[VPT];
#pragma unroll
  for (int i = 0; i < VPT; ++i) v[i] = src[i * THREADS + t];

  // Zero all hists (each used exactly once per block).
#pragma unroll
  for (int i = 0; i < NB1 / THREADS; ++i) h1[t + i * THREADS] = 0;
#pragma unroll
  for (int i = 0; i < NB2 / THREADS; ++i) h2[t + i * THREADS] = 0;
#pragma unroll
  for (int i = 0; i < NB3 / THREADS; ++i) h3[t + i * THREADS] = 0;
  __syncthreads();

  // P1: bits [30:20] -> h1
#pragma unroll
  for (int i = 0; i < VPT; ++i) {
    atomicAdd(&h1[(v[i].x & 0x7fffffffu) >> 20], 1u);
    atomicAdd(&h1[(v[i].y & 0x7fffffffu) >> 20], 1u);
    atomicAdd(&h1[(v[i].z & 0x7fffffffu) >> 20], 1u);
    atomicAdd(&h1[(v[i].w & 0x7fffffffu) >> 20], 1u);
  }
  __syncthreads();
  if (t < 64) find_bin_wave0<NB1>(h1, K_SEL, bc);
  __syncthreads();
  const unsigned T1 = bc[0];
  unsigned kRem = bc[1];

  // P2: among (a>>20)==T1, bits [19:10] -> h2 (~2-5% of elements hit)
#pragma unroll
  for (int i = 0; i < VPT; ++i) {
    unsigned a;
    a = v[i].x & 0x7fffffffu; if ((a >> 20) == T1) atomicAdd(&h2[(a >> 10) & (NB2 - 1)], 1u);
    a = v[i].y & 0x7fffffffu; if ((a >> 20) == T1) atomicAdd(&h2[(a >> 10) & (NB2 - 1)], 1u);
    a = v[i].z & 0x7fffffffu; if ((a >> 20) == T1) atomicAdd(&h2[(a >> 10) & (NB2 - 1)], 1u);
    a = v[i].w & 0x7fffffffu; if ((a >> 20) == T1) atomicAdd(&h2[(a >> 10) & (NB2 - 1)], 1u);
  }
  __syncthreads();
  if (t < 64) find_bin_wave0<NB2>(h2, kRem, bc);
  __syncthreads();
  const unsigned pref2 = (T1 << 10) | bc[0];   // == a>>10 of threshold
  kRem = bc[1];

  // P3: among (a>>10)==pref2, bits [9:0] -> h3
#pragma unroll
  for (int i = 0; i < VPT; ++i) {
    unsigned a;
    a = v[i].x & 0x7fffffffu; if ((a >> 10) == pref2) atomicAdd(&h3[a & (NB3 - 1)], 1u);
    a = v[i].y & 0x7fffffffu; if ((a >> 10) == pref2) atomicAdd(&h3[a & (NB3 - 1)], 1u);
    a = v[i].z & 0x7fffffffu; if ((a >> 10) == pref2) atomicAdd(&h3[a & (NB3 - 1)], 1u);
    a = v[i].w & 0x7fffffffu; if ((a >> 10) == pref2) atomicAdd(&h3[a & (NB3 - 1)], 1u);
  }
  __syncthreads();
  if (t < 64) find_bin_wave0<NB3>(h3, kRem, bc);
  __syncthreads();
  const unsigned thr = (pref2 << 10) | bc[0];  // exact k-th largest |x| bits

  // Masked NON-TEMPORAL store (>= keeps ties, same as reference). Output has
  // zero reuse -> bypass L2/L3 so the input stream stays cache-resident.
  // Mask in place: no new live ranges vs R7's store loop.
#pragma unroll
  for (int i = 0; i < VPT; ++i) {
    uint32x4 w;
    w.x = v[i].x; w.y = v[i].y; w.z = v[i].z; w.w = v[i].w;
    w.x = ((w.x & 0x7fffffffu) >= thr) ? w.x : 0u;
    w.y = ((w.y & 0x7fffffffu) >= thr) ? w.y : 0u;
    w.z = ((w.z & 0x7fffffffu) >= thr) ? w.z : 0u;
    w.w = ((w.w & 0x7fffffffu) >= thr) ? w.w : 0u;
    __builtin_nontemporal_store(w, &dst[i * THREADS + t]);
  }
}

extern "C" void kernel_launch(void* const* d_in, const int* in_sizes, int n_in,
                              void* d_out, int out_size, void* d_ws, size_t ws_size,
                              hipStream_t stream) {
  (void)n_in; (void)d_ws; (void)ws_size; (void)out_size;
  const float* x = (const float*)d_in[0];
  float* out = (float*)d_out;
  const int rows = in_sizes[0] / HW;   // 4096
  sparsify_topk_kernel<<<dim3(rows), dim3(THREADS), 0, stream>>>(x, out);
}